// Round 5
// baseline (18.059 us; speedup 1.0000x reference)
//
#include <hip/hip_runtime.h>

// B-spline activation (KAN-style), fp32.
// x: (8192, 1024) f32, coeff: (1024, 10) f32, out: (8192, 1024) f32.
// Round-4: transposed LDS panel (slot-major, column stride 256 == 0 mod 32)
// -> tap bank = fg mod 32, conflict-free INDEPENDENT of the data-dependent j
// (round-3's 17*fg+j pattern collided ~4-way on random j). Taps are 4x
// ds_read_b32 with immediate offsets 0/1024/2048/3072 off one vaddr.
// All 4 float4 x-loads hoisted into statically-indexed regs before compute.

constexpr int NB = 10;           // N_BASES
constexpr int THREADS = 256;
constexpr int GRID = 2048;
constexpr int ITERS = 4;         // 2048 blocks * 4 iters * 4096 elems = 2^23

__global__ __launch_bounds__(THREADS) void bspline_act_kernel(
    const float* __restrict__ x,
    const float* __restrict__ coeff,
    float* __restrict__ out)
{
    // lds[c][r2]: c = padded slot 0..15 (basis n at slot n+3), r2 = swizzled row.
    __shared__ float lds[16 * 256];             // 16 KB -> 8 blocks/CU
    const int t = threadIdx.x;
    const int b = blockIdx.x;
    const int panel = b & 3;                    // 256-feature panel
    const int rg = b >> 2;                      // row-group id, 0..511
    const int fg = t & 63;                      // feature group (4 features)
    const int wr = t >> 6;                      // batch-row offset within group

    // Zero the 6 pad planes (slots 0..2 and 13..15), bank = t mod 32: free.
    lds[0 * 256 + t] = 0.0f;
    lds[1 * 256 + t] = 0.0f;
    lds[2 * 256 + t] = 0.0f;
    lds[13 * 256 + t] = 0.0f;
    lds[14 * 256 + t] = 0.0f;
    lds[15 * 256 + t] = 0.0f;

    // Stage the 256x10 coeff panel, coalesced global reads; transposed +
    // swizzled placement (one-time; write conflicts are amortized away).
    const float* src = coeff + panel * 256 * NB;
    #pragma unroll
    for (int it = 0; it < NB; ++it) {
        const int idx = t + it * THREADS;       // 0..2559
        const float v = src[idx];
        const int r = idx / NB;                 // magic-mul, no HW divide
        const int c = idx - r * NB;
        const int r2 = ((r & 3) << 6) | (r >> 2);   // element-major swizzle
        lds[(c + 3) * 256 + r2] = v;
    }
    __syncthreads();

    // Hoist all x loads: 4 independent float4 loads in flight.
    float4 xv[ITERS];
    int E4[ITERS];
    #pragma unroll
    for (int k = 0; k < ITERS; ++k) {
        const int row = 4 * (rg + k * 512) + wr;          // batch row
        E4[k] = row * 256 + panel * 64 + fg;              // float4 index
        xv[k] = reinterpret_cast<const float4*>(x)[E4[k]];
    }

    const float* lbase = lds + fg;   // + e*64 + (j+tap)*256

    #pragma unroll
    for (int k = 0; k < ITERS; ++k) {
        const float xs[4] = {xv[k].x, xv[k].y, xv[k].z, xv[k].w};
        float r[4];
        #pragma unroll
        for (int e = 0; e < 4; ++e) {
            const float xc = fminf(fmaxf(xs[e], -1.0f), 1.0f);
            const float u = fmaf(xc, 6.5f, 6.5f);         // knot units [0,13]
            const float jf = fminf(truncf(u), 12.0f);
            const float tt = u - jf;                      // [0,1]
            const int j = (int)jf;

            // Cardinal cubic B-spline weights (partition of unity).
            const float t2 = tt * tt;
            const float a = 1.0f - tt;
            const float Ns0 = a * a * a * (1.0f / 6.0f);
            const float Ns3 = t2 * tt * (1.0f / 6.0f);
            const float p = fmaf(0.5f, tt, -1.0f);
            const float Ns1 = fmaf(p, t2, 2.0f / 3.0f);
            const float Ns2 = 1.0f - Ns0 - Ns1 - Ns3;

            // Taps at slots j..j+3, plane stride 256 floats (1024 B imm offsets).
            const float* crow = lbase + e * 64 + (j << 8);
            float res = Ns0 * crow[0];
            res = fmaf(Ns1, crow[256], res);
            res = fmaf(Ns2, crow[512], res);
            res = fmaf(Ns3, crow[768], res);
            // x==+1: j=12, Ns0=0, slots 13..15 are zero -> res=0 (ref quirk).
            r[e] = res;
        }
        const float4 ov = {r[0], r[1], r[2], r[3]};
        reinterpret_cast<float4*>(out)[E4[k]] = ov;
    }
}

extern "C" void kernel_launch(void* const* d_in, const int* in_sizes, int n_in,
                              void* d_out, int out_size, void* d_ws, size_t ws_size,
                              hipStream_t stream) {
    const float* x = (const float*)d_in[0];
    const float* coeff = (const float*)d_in[1];
    float* out = (float*)d_out;
    hipLaunchKernelGGL(bspline_act_kernel, dim3(GRID), dim3(THREADS), 0, stream,
                       x, coeff, out);
}

// Round 6
// 15.931 us; speedup vs baseline: 1.1336x; 1.1336x over previous
//
#include <hip/hip_runtime.h>

// B-spline activation (KAN-style), fp32.
// x: (8192, 1024) f32, coeff: (1024, 10) f32, out: (8192, 1024) f32.
// Round-5: per-(feature, interval) power-basis float4 in LDS.
//   P_j(tt) = a0 + a1 tt + a2 tt^2 + a3 tt^3, (a) = M * (c[j-3..j], pads=0).
// Tap fetch = ONE ds_read_b128; plane stride 2048B == 0 mod 128 -> bank index
// is j-INDEPENDENT; lanes read consecutive 16B chunks (conflict-free, m134
// pattern); wr-halves broadcast. Inner math = 3 Horner FMAs.
// Round-4 lesson: transposed-scalar taps exceeded ds_read2 offset reach
// (1024B > 1020B max) -> 16 ds_read_b32/iter; access count is the currency.

constexpr int NB = 10;           // N_BASES
constexpr int THREADS = 256;
constexpr int GRID = 2048;
constexpr int ITERS = 4;
constexpr int PROWS = 128;       // features per panel (8 panels)
constexpr int NJ = 13;           // intervals

__global__ __launch_bounds__(THREADS) void bspline_act_kernel(
    const float* __restrict__ x,
    const float* __restrict__ coeff,
    float* __restrict__ out)
{
    // lds4[j * PROWS + s]; slot s holds logical row r(s) = ((s&31)<<2)|(s>>5),
    // so the reader's row 4*fg+e lives at slot e*32+fg.
    __shared__ float4 lds4[NJ * PROWS];          // 26 KB -> 6 blocks/CU
    const int t = threadIdx.x;
    const int b = blockIdx.x;
    const int panel = b & 7;                     // 128-feature panel
    const int rg = b >> 3;                       // 0..255
    const int fg = t & 31;                       // feature group (4 features)
    const int wr = t >> 5;                       // 0..7: batch row within stripe

    // Staging: threads 0..127 each build one row's 13 interval-polynomials.
    if (t < PROWS) {
        const int r = ((t & 31) << 2) | (t >> 5);        // r2(r) == t
        const float* src = coeff + (panel * PROWS + r) * NB;
        float w[16];
        w[0] = w[1] = w[2] = 0.0f;
        w[13] = w[14] = w[15] = 0.0f;
        #pragma unroll
        for (int c = 0; c < 5; ++c) {
            const float2 p = reinterpret_cast<const float2*>(src)[c];
            w[3 + 2 * c] = p.x;
            w[4 + 2 * c] = p.y;
        }
        #pragma unroll
        for (int j = 0; j < NJ; ++j) {
            const float d0 = w[j], d1 = w[j + 1], d2 = w[j + 2], d3 = w[j + 3];
            float4 a;
            a.x = fmaf(4.0f, d1, d0 + d2) * (1.0f / 6.0f);     // a0
            a.y = (d2 - d0) * 0.5f;                            // a1
            a.z = (d0 + d2) * 0.5f - d1;                       // a2
            a.w = (d3 - d0) * (1.0f / 6.0f) + (d1 - d2) * 0.5f;// a3
            lds4[j * PROWS + t] = a;   // consecutive slots per lane: conflict-free
        }
    }
    __syncthreads();

    // Hoist all x loads: 4 independent float4 loads in flight.
    float4 xv[ITERS];
    int E4[ITERS];
    #pragma unroll
    for (int k = 0; k < ITERS; ++k) {
        const int row = (rg + k * 256) * 8 + wr;         // batch row
        E4[k] = row * 256 + panel * 32 + fg;             // float4 index
        xv[k] = reinterpret_cast<const float4*>(x)[E4[k]];
    }

    const float4* lbase = lds4 + fg;    // + e*32 + j*PROWS

    #pragma unroll
    for (int k = 0; k < ITERS; ++k) {
        const float xs[4] = {xv[k].x, xv[k].y, xv[k].z, xv[k].w};
        float res[4];
        #pragma unroll
        for (int e = 0; e < 4; ++e) {
            const float xc = fminf(fmaxf(xs[e], -1.0f), 1.0f);
            const float u = fmaf(xc, 6.5f, 6.5f);        // knot units [0,13]
            const float jf = fminf(truncf(u), 12.0f);
            const float tt = u - jf;                     // [0,1]
            const int j = (int)jf;

            const float4 a = lbase[e * 32 + j * PROWS];  // 1x ds_read_b128
            float r = fmaf(a.w, tt, a.z);
            r = fmaf(r, tt, a.y);
            r = fmaf(r, tt, a.x);
            // x==+1 (j=12, tt=1): pads make a0+a1+a2+a3 ~ 0 (~1e-7|c9|),
            // matching the reference's empty top-knot indicator to fp noise.
            res[e] = r;
        }
        const float4 ov = {res[0], res[1], res[2], res[3]};
        reinterpret_cast<float4*>(out)[E4[k]] = ov;
    }
}

extern "C" void kernel_launch(void* const* d_in, const int* in_sizes, int n_in,
                              void* d_out, int out_size, void* d_ws, size_t ws_size,
                              hipStream_t stream) {
    const float* x = (const float*)d_in[0];
    const float* coeff = (const float*)d_in[1];
    float* out = (float*)d_out;
    hipLaunchKernelGGL(bspline_act_kernel, dim3(GRID), dim3(THREADS), 0, stream,
                       x, coeff, out);
}